// Round 3
// baseline (352.961 us; speedup 1.0000x reference)
//
#include <hip/hip_runtime.h>

#define NNODES 50000
#define NEDGES 800000
#define DIM 64
#define EBLOCKS ((NEDGES + 255) / 256)   // 3125 edge blocks in K1
#define GBLOCKS ((NNODES + 15) / 16)     // 3125 gemm blocks

// ---------------------------------------------------------------------------
// Shared GEMM tile body: H[rowBase:rowBase+16, :] = act(X) @ W + b
template <bool RELU>
__device__ __forceinline__ void gemm_tile(const float* __restrict__ X,
                                          const float* __restrict__ W,
                                          const float* __restrict__ b,
                                          float* __restrict__ H, int rowBase,
                                          float* Ws, float (*Xs)[65]) {
    const int tid = threadIdx.x;
    // stage W: 4096 floats = 1024 float4
    {
        const float4* Wv = (const float4*)W;
        float4* Wsv = (float4*)Ws;
#pragma unroll
        for (int i = 0; i < 4; i++) Wsv[tid + 256 * i] = Wv[tid + 256 * i];
    }
    // stage 16 rows of X
    {
        int r = tid >> 4;
        int c4 = tid & 15;
        int gr = rowBase + r;
        float4 v = make_float4(0.f, 0.f, 0.f, 0.f);
        if (gr < NNODES) v = ((const float4*)X)[gr * 16 + c4];
        if (RELU) {
            v.x = fmaxf(v.x, 0.f); v.y = fmaxf(v.y, 0.f);
            v.z = fmaxf(v.z, 0.f); v.w = fmaxf(v.w, 0.f);
        }
        Xs[r][c4 * 4 + 0] = v.x;
        Xs[r][c4 * 4 + 1] = v.y;
        Xs[r][c4 * 4 + 2] = v.z;
        Xs[r][c4 * 4 + 3] = v.w;
    }
    __syncthreads();

    const int r = tid >> 4;
    const int c0 = (tid & 15) * 4;
    float a0 = b[c0 + 0], a1 = b[c0 + 1], a2 = b[c0 + 2], a3 = b[c0 + 3];
#pragma unroll
    for (int k = 0; k < 64; k++) {
        float xv = Xs[r][k];
        float4 wv = *(const float4*)&Ws[k * 64 + c0];
        a0 = fmaf(xv, wv.x, a0);
        a1 = fmaf(xv, wv.y, a1);
        a2 = fmaf(xv, wv.z, a2);
        a3 = fmaf(xv, wv.w, a3);
    }
    int gr = rowBase + r;
    if (gr < NNODES) {
        float4 o = make_float4(a0, a1, a2, a3);
        *(float4*)&H[gr * 64 + c0] = o;
    }
}

// ---------------------------------------------------------------------------
// K1: blocks [0,EBLOCKS): deg[row]+=ew (atomic), rank[e]=count[col]++ (atomic)
//     blocks [EBLOCKS,..): GEMM1  h = x @ W1 + b1   (atomic-bound and
//     VALU-bound work co-scheduled in one dispatch — gemm rides free)
__global__ __launch_bounds__(256) void k1_kernel(const int* __restrict__ ei,
                                                 const float* __restrict__ ew,
                                                 float* __restrict__ deg,
                                                 int* __restrict__ count,
                                                 int* __restrict__ rank_,
                                                 const float* __restrict__ X,
                                                 const float* __restrict__ W,
                                                 const float* __restrict__ b,
                                                 float* __restrict__ H) {
    __shared__ float Ws[64 * 64];
    __shared__ float Xs[16][65];
    int bid = blockIdx.x;
    if (bid < EBLOCKS) {
        int e = bid * 256 + threadIdx.x;
        if (e < NEDGES) {
            int r = ei[e];
            int c = ei[NEDGES + e];
            atomicAdd(&deg[r], ew[e]);
            rank_[e] = atomicAdd(&count[c], 1);   // old value == rank within col
        }
        return;
    }
    gemm_tile<false>(X, W, b, H, (bid - EBLOCKS) * 16, Ws, Xs);
}

// ---------------------------------------------------------------------------
// Single-block exclusive scan: count[N] -> rowptr[N], rowptr[N] = E
__global__ __launch_bounds__(1024) void scan_kernel(const int* __restrict__ count,
                                                    int* __restrict__ rowptr) {
    __shared__ int tmp[1024];
    const int CH = (NNODES + 1023) / 1024;  // 49
    int t = threadIdx.x;
    int base = t * CH;
    int s = 0;
    for (int k = 0; k < CH; k++) {
        int i = base + k;
        if (i < NNODES) s += count[i];
    }
    tmp[t] = s;
    __syncthreads();
    for (int off = 1; off < 1024; off <<= 1) {
        int add = (t >= off) ? tmp[t - off] : 0;
        __syncthreads();
        tmp[t] += add;
        __syncthreads();
    }
    int run = tmp[t] - s;  // exclusive prefix
    for (int k = 0; k < CH; k++) {
        int i = base + k;
        if (i < NNODES) { rowptr[i] = run; run += count[i]; }
    }
    if (t == 0) rowptr[NNODES] = NEDGES;
}

// ---------------------------------------------------------------------------
// fill: edata[rowptr[col]+rank[e]] = (row, norm).  NO atomics.
// norm computed inline from raw deg (saves a dis pass; deg is 200 KB, L2-hot).
__global__ __launch_bounds__(256) void fill_kernel(const int* __restrict__ ei,
                                                   const float* __restrict__ ew,
                                                   const float* __restrict__ deg,
                                                   const int* __restrict__ rank_,
                                                   const int* __restrict__ rowptr,
                                                   int2* __restrict__ edata) {
    int e = blockIdx.x * 256 + threadIdx.x;
    if (e >= NEDGES) return;
    int r = ei[e];
    int c = ei[NEDGES + e];
    float dr = deg[r];
    float dc = deg[c];
    float nv = ((dr > 0.f) ? rsqrtf(dr) : 0.f) * ew[e] * ((dc > 0.f) ? rsqrtf(dc) : 0.f);
    edata[rowptr[c] + rank_[e]] = make_int2(r, __float_as_int(nv));
}

// ---------------------------------------------------------------------------
// gather: Out[n,:] = sum_{e in CSR[n]} norm[e] * H[row[e],:]
// One wave per node, lane = feature. 4x unrolled, dual accumulators.
__global__ __launch_bounds__(256) void gather_kernel(const int* __restrict__ rowptr,
                                                     const int2* __restrict__ edata,
                                                     const float* __restrict__ H,
                                                     float* __restrict__ Out, int N) {
    int node = blockIdx.x * 4 + (threadIdx.x >> 6);
    int lane = threadIdx.x & 63;
    if (node >= N) return;
    int s = rowptr[node];
    int e_end = rowptr[node + 1];
    float acc0 = 0.0f, acc1 = 0.0f;
    for (int base = s; base < e_end; base += 64) {
        int m = e_end - base;
        if (m > 64) m = 64;
        int2 d = make_int2(0, 0);
        if (base + lane < e_end) d = edata[base + lane];
        int j = 0;
        for (; j + 4 <= m; j += 4) {
            int r0 = __shfl(d.x, j + 0);
            int r1 = __shfl(d.x, j + 1);
            int r2 = __shfl(d.x, j + 2);
            int r3 = __shfl(d.x, j + 3);
            float n0 = __int_as_float(__shfl(d.y, j + 0));
            float n1 = __int_as_float(__shfl(d.y, j + 1));
            float n2 = __int_as_float(__shfl(d.y, j + 2));
            float n3 = __int_as_float(__shfl(d.y, j + 3));
            float h0 = H[r0 * DIM + lane];
            float h1 = H[r1 * DIM + lane];
            float h2 = H[r2 * DIM + lane];
            float h3 = H[r3 * DIM + lane];
            acc0 = fmaf(n0, h0, acc0);
            acc1 = fmaf(n1, h1, acc1);
            acc0 = fmaf(n2, h2, acc0);
            acc1 = fmaf(n3, h3, acc1);
        }
        for (; j < m; j++) {
            int r0 = __shfl(d.x, j);
            float n0 = __int_as_float(__shfl(d.y, j));
            acc0 = fmaf(n0, H[r0 * DIM + lane], acc0);
        }
    }
    Out[node * DIM + lane] = acc0 + acc1;
}

// ---------------------------------------------------------------------------
// GEMM2 standalone (ReLU fused into input load)
__global__ __launch_bounds__(256) void gemm2_kernel(const float* __restrict__ X,
                                                    const float* __restrict__ W,
                                                    const float* __restrict__ b,
                                                    float* __restrict__ H) {
    __shared__ float Ws[64 * 64];
    __shared__ float Xs[16][65];
    gemm_tile<true>(X, W, b, H, blockIdx.x * 16, Ws, Xs);
}

// ---------------------------------------------------------------------------
extern "C" void kernel_launch(void* const* d_in, const int* in_sizes, int n_in,
                              void* d_out, int out_size, void* d_ws, size_t ws_size,
                              hipStream_t stream) {
    const float* x  = (const float*)d_in[0];
    const int*   ei = (const int*)d_in[1];   // [2, E] int32
    const float* ew = (const float*)d_in[2];
    const float* W1 = (const float*)d_in[3];
    const float* b1 = (const float*)d_in[4];
    const float* W2 = (const float*)d_in[5];
    const float* b2 = (const float*)d_in[6];
    float* out = (float*)d_out;

    const int N = NNODES, E = NEDGES;

    char* ws = (char*)d_ws;
    size_t off = 0;
    auto alloc = [&](size_t bytes) { char* p = ws + off; off += (bytes + 255) & ~size_t(255); return p; };
    float* deg    = (float*)alloc((size_t)N * 4);        // raw weighted degree
    int*   count  = (int*)  alloc((size_t)N * 4);
    int*   rowptr = (int*)  alloc((size_t)(N + 1) * 4);
    int*   rank_  = (int*)  alloc((size_t)E * 4);
    int2*  edata  = (int2*) alloc((size_t)E * 8);
    float* h      = (float*)alloc((size_t)N * DIM * 4);  // reused h1/h2
    float* agg1   = (float*)alloc((size_t)N * DIM * 4);

    // deg and count are the first two (256B-aligned) regions — one memset
    hipMemsetAsync(deg, 0, 2 * (((size_t)N * 4 + 255) & ~size_t(255)), stream);

    // K1: CSR histogram + degree atomics, GEMM1 fused as trailing blocks
    k1_kernel<<<EBLOCKS + GBLOCKS, 256, 0, stream>>>(ei, ew, deg, count, rank_,
                                                     x, W1, b1, h);
    scan_kernel<<<1, 1024, 0, stream>>>(count, rowptr);
    fill_kernel<<<(E + 255) / 256, 256, 0, stream>>>(ei, ew, deg, rank_, rowptr, edata);

    // layer 1 aggregation
    gather_kernel<<<(N + 3) / 4, 256, 0, stream>>>(rowptr, edata, h, agg1, N);
    // layer 2
    gemm2_kernel<<<GBLOCKS, 256, 0, stream>>>(agg1, W2, b2, h);
    gather_kernel<<<(N + 3) / 4, 256, 0, stream>>>(rowptr, edata, h, out, N);
}